// Round 15
// baseline (146.872 us; speedup 1.0000x reference)
//
#include <hip/hip_runtime.h>

#define N_NODES 50000
#define N_EDGES 800000
#define D_IN 128
#define HIDDEN 64
#define N_CLASSES 2
#define NBUK 782        // ceil(50000/64) buckets of 64 nodes
#define NBUK_P 784      // padded stride (bhist rows)
#define NBLK 196        // edge-chunk blocks: 196*4096 >= 800000
#define NBLK_P 200      // padded stride (excT rows)
#define NE4 200000      // N_EDGES/4
#define XPAD 136        // fp16 LDS row stride (128 + 8 pad)

typedef _Float16 half4v __attribute__((ext_vector_type(4)));
typedef _Float16 h8 __attribute__((ext_vector_type(8)));
typedef float f4 __attribute__((ext_vector_type(4)));

// ---------------- phase 1: per-chunk LDS histogram over dst buckets ----------------

__global__ __launch_bounds__(256) void k_hist(const int4* __restrict__ dst4,
                                              int* __restrict__ bhist) {
    __shared__ int hist[NBUK];
    int t = threadIdx.x;
    for (int i = t; i < NBUK; i += 256) hist[i] = 0;
    __syncthreads();
    int base4 = blockIdx.x * 1024;
#pragma unroll
    for (int k = 0; k < 4; k++) {
        int idx = base4 + k * 256 + t;
        if (idx < NE4) {
            int4 d = dst4[idx];
            atomicAdd(&hist[d.x >> 6], 1);
            atomicAdd(&hist[d.y >> 6], 1);
            atomicAdd(&hist[d.z >> 6], 1);
            atomicAdd(&hist[d.w >> 6], 1);
        }
    }
    __syncthreads();
    for (int i = t; i < NBUK; i += 256) bhist[blockIdx.x * NBUK_P + i] = hist[i];
}

// ---------------- phase 2: column scan over 196 chunks; excT transposed ----------------

__global__ __launch_bounds__(256) void k_colscan(const int* __restrict__ bhist,
                                                 int* __restrict__ excT,
                                                 int* __restrict__ colsum) {
    __shared__ int part[256];
    int b = blockIdx.x;   // bucket
    int t = threadIdx.x;
    int v = (t < NBLK) ? bhist[t * NBUK_P + b] : 0;
    part[t] = v;
    __syncthreads();
    for (int off = 1; off < 256; off <<= 1) {
        int p = (t >= off) ? part[t - off] : 0;
        __syncthreads();
        part[t] += p;
        __syncthreads();
    }
    if (t < NBLK) excT[b * NBLK_P + t] = part[t] - v;  // exclusive
    if (t == 255) colsum[b] = part[255];
}

// ---------------- phase 3: scatter with inline bucket-offset scan ----------------
// Each of 196 blocks redundantly scans the 782 colsums (L2-hot) -> no separate
// dispatch, no grid.sync (R9: grid.sync ~75us). pk = (src<<7)|(dst&63).
// ebin stores are non-temporal: single-use stream, keep L2 for hs.

__global__ __launch_bounds__(256) void k_binA2s(const int4* __restrict__ src4,
                                                const int4* __restrict__ dst4,
                                                const int* __restrict__ excT,
                                                const int* __restrict__ colsum,
                                                int* __restrict__ bucket_off,
                                                int* __restrict__ row_ptr,
                                                int* __restrict__ ebin) {
    __shared__ int part[256];
    __shared__ int cur[NBUK];
    const int b = blockIdx.x;
    const int t = threadIdx.x;

    int v[4];
    int s = 0;
#pragma unroll
    for (int i = 0; i < 4; i++) {
        int idx = t * 4 + i;
        v[i] = (idx < NBUK) ? colsum[idx] : 0;
        s += v[i];
    }
    part[t] = s;
    __syncthreads();
    for (int off = 1; off < 256; off <<= 1) {
        int p = (t >= off) ? part[t - off] : 0;
        __syncthreads();
        part[t] += p;
        __syncthreads();
    }
    int run = (t == 0) ? 0 : part[t - 1];
#pragma unroll
    for (int i = 0; i < 4; i++) {
        int idx = t * 4 + i;
        if (idx < NBUK) {
            cur[idx] = run + excT[idx * NBLK_P + b];
            if (b == 0) bucket_off[idx] = run;
            run += v[i];
        } else if (idx == NBUK && b == 0) {
            bucket_off[idx] = run;  // == N_EDGES
        }
    }
    if (b == 0 && t == 0) row_ptr[N_NODES] = N_EDGES;
    __syncthreads();

    int base4 = b * 1024;
#pragma unroll
    for (int k = 0; k < 4; k++) {
        int idx = base4 + k * 256 + t;
        if (idx < NE4) {
            int4 sv = src4[idx];
            int4 d = dst4[idx];
            int p0 = atomicAdd(&cur[d.x >> 6], 1);
            int p1 = atomicAdd(&cur[d.y >> 6], 1);
            int p2 = atomicAdd(&cur[d.z >> 6], 1);
            int p3 = atomicAdd(&cur[d.w >> 6], 1);
            __builtin_nontemporal_store((sv.x << 7) | (d.x & 63), &ebin[p0]);
            __builtin_nontemporal_store((sv.y << 7) | (d.y & 63), &ebin[p1]);
            __builtin_nontemporal_store((sv.z << 7) | (d.z & 63), &ebin[p2]);
            __builtin_nontemporal_store((sv.w << 7) | (d.w & 63), &ebin[p3]);
        }
    }
}

// ---------------- phase 4 (merged): per-bucket CSR + MFMA fp16 GEMM tile ----------------
// Block b owns nodes [b*64, b*64+64): builds their CSR rows, keeps dinv in LDS,
// computes hs = (x@W1)*dinv via v_mfma_f32_16x16x32_f16 (fp32 accumulate).
//   A-frag:  m = lane&15, k = (lane>>4)*8 + j
//   B-frag:  n = lane&15, k = (lane>>4)*8 + j   (W1 transposed Wt[n][k])
//   C/D:     n = lane&15, m = (lane>>4)*4 + reg
// rec stores non-temporal (read once by agg kernels; keep L2 for hs).

__global__ __launch_bounds__(256) void k_csr_gemm(
    const int* __restrict__ ebin, const int* __restrict__ bucket_off,
    const float* __restrict__ x, const float* __restrict__ W1,
    int* __restrict__ row_ptr, float* __restrict__ dinv_g,
    int* __restrict__ rec, _Float16* __restrict__ hs)
{
    __shared__ _Float16 xs[64 * XPAD];   // 17.0 KB
    __shared__ _Float16 Wt[64 * XPAD];   // 17.0 KB  (Wt[n][k])
    __shared__ int cnt[64];
    __shared__ int cur[64];
    __shared__ float sdinv[64];
    const int b = blockIdx.x;
    const int t = threadIdx.x;
    const int row0 = b * 64;

    // --- stage x tile fp32->fp16 ---
    for (int i4 = t; i4 < 64 * D_IN / 4; i4 += 256) {
        int r = i4 >> 5;
        int k4 = (i4 & 31) << 2;
        int grow = row0 + r;
        half4v hv;
        if (grow < N_NODES) {
            float4 v = *(const float4*)&x[grow * D_IN + k4];
            hv.x = (_Float16)v.x; hv.y = (_Float16)v.y;
            hv.z = (_Float16)v.z; hv.w = (_Float16)v.w;
        } else {
            hv.x = hv.y = hv.z = hv.w = (_Float16)0.f;  // pad rows stay zero
        }
        *(half4v*)&xs[r * XPAD + k4] = hv;
    }
    // --- stage W1 transposed fp32->fp16 ---
    for (int i4 = t; i4 < D_IN * HIDDEN / 4; i4 += 256) {
        float4 v = *(const float4*)&W1[i4 * 4];
        int k = i4 >> 4;
        int n = (i4 & 15) << 2;
        Wt[(n + 0) * XPAD + k] = (_Float16)v.x;
        Wt[(n + 1) * XPAD + k] = (_Float16)v.y;
        Wt[(n + 2) * XPAD + k] = (_Float16)v.z;
        Wt[(n + 3) * XPAD + k] = (_Float16)v.w;
    }

    // --- CSR phase: degree count + wave scan + node-sorted scatter ---
    if (t < 64) cnt[t] = 0;
    __syncthreads();
    int beg = bucket_off[b], end = bucket_off[b + 1];
    for (int i = beg + t; i < end; i += 256) atomicAdd(&cnt[ebin[i] & 63], 1);
    __syncthreads();
    if (t < 64) {
        int deg = cnt[t];
        int sum = deg;  // inclusive wave scan over 64 lanes
#pragma unroll
        for (int off = 1; off < 64; off <<= 1) {
            int v = __shfl_up(sum, off, 64);
            if (t >= off) sum += v;
        }
        int rp = beg + sum - deg;
        cur[t] = rp;
        float di = rsqrtf((float)(deg + 1));  // +1 self-loop
        sdinv[t] = di;
        int node = row0 + t;
        if (node < N_NODES) {
            row_ptr[node] = rp;
            dinv_g[node] = di;
        }
    }
    __syncthreads();
    for (int i = beg + t; i < end; i += 256) {
        int pk = ebin[i];
        int pos = atomicAdd(&cur[pk & 63], 1);
        __builtin_nontemporal_store(pk >> 7, &rec[pos]);
    }
    __syncthreads();  // staging + CSR complete

    // --- MFMA: wave w owns rows [w*16, w*16+16); 4 n-tiles; K=128 in 4 steps ---
    const int w = t >> 6;
    const int L = t & 63;
    const int mrow = w * 16 + (L & 15);
    const int qk = (L >> 4) * 8;
    f4 acc0 = {0.f, 0.f, 0.f, 0.f}, acc1 = acc0, acc2 = acc0, acc3 = acc0;
#pragma unroll
    for (int ks = 0; ks < D_IN; ks += 32) {
        h8 a = *(const h8*)&xs[mrow * XPAD + ks + qk];
        h8 b0 = *(const h8*)&Wt[(0 * 16 + (L & 15)) * XPAD + ks + qk];
        h8 b1 = *(const h8*)&Wt[(1 * 16 + (L & 15)) * XPAD + ks + qk];
        h8 b2 = *(const h8*)&Wt[(2 * 16 + (L & 15)) * XPAD + ks + qk];
        h8 b3 = *(const h8*)&Wt[(3 * 16 + (L & 15)) * XPAD + ks + qk];
        acc0 = __builtin_amdgcn_mfma_f32_16x16x32_f16(a, b0, acc0, 0, 0, 0);
        acc1 = __builtin_amdgcn_mfma_f32_16x16x32_f16(a, b1, acc1, 0, 0, 0);
        acc2 = __builtin_amdgcn_mfma_f32_16x16x32_f16(a, b2, acc2, 0, 0, 0);
        acc3 = __builtin_amdgcn_mfma_f32_16x16x32_f16(a, b3, acc3, 0, 0, 0);
    }

    // --- epilogue: hs[node][col] = acc * dinv ---
    const int n0 = L & 15;
#pragma unroll
    for (int j = 0; j < 4; j++) {
        int m = w * 16 + (L >> 4) * 4 + j;
        float di = sdinv[m];
        size_t base = (size_t)(row0 + m) * HIDDEN;
        hs[base + 0 * 16 + n0] = (_Float16)(acc0[j] * di);
        hs[base + 1 * 16 + n0] = (_Float16)(acc1[j] * di);
        hs[base + 2 * 16 + n0] = (_Float16)(acc2[j] * di);
        hs[base + 3 * 16 + n0] = (_Float16)(acc3[j] * di);
    }
}

// ---------------- fused agg1 + relu + layer2: 8 nodes per wave, 64 gathers in flight ----------------
// 8 lanes per node (g = feature-octet, 16B h8 load covers 8 features).
// Per 8-edge window: 8 independent 16B gathers per lane-group -> 64/wave.
// Reduction chains stay within each 8-lane group (lane0 reads lanes 1/2/4).

__global__ __launch_bounds__(256) void k_agg1_l2(
    const _Float16* __restrict__ hs, const int* __restrict__ row_ptr,
    const int* __restrict__ rec, const float* __restrict__ dinv,
    const float* __restrict__ b1, const float* __restrict__ W2,
    float* __restrict__ zs)
{
    const int node = blockIdx.x * 32 + (threadIdx.x >> 3);  // grid 1563
    const int g = threadIdx.x & 7;       // lane in 8-lane group == feature octet
    const int gbase = threadIdx.x & 56;  // group's base lane within the wave
    if (node >= N_NODES) return;
    const h8* H = (const h8*)hs;

    float di = dinv[node];
    float acc[8];
#pragma unroll
    for (int i = 0; i < 8; i++) acc[i] = 0.f;

    int beg = row_ptr[node];
    int end = row_ptr[node + 1];

    for (int base = beg; base < end; base += 8) {
        int n = end - base;
        if (n > 8) n = 8;
        int r = N_NODES;  // pad: zero row of hs
        if (g < n) r = __builtin_nontemporal_load(&rec[base + g]);
        int s0 = __shfl(r, gbase + 0, 64);
        int s1 = __shfl(r, gbase + 1, 64);
        int s2 = __shfl(r, gbase + 2, 64);
        int s3 = __shfl(r, gbase + 3, 64);
        int s4 = __shfl(r, gbase + 4, 64);
        int s5 = __shfl(r, gbase + 5, 64);
        int s6 = __shfl(r, gbase + 6, 64);
        int s7 = __shfl(r, gbase + 7, 64);
        // pad edges (slot >= n) have r==N_NODES -> zero row, harmless
        h8 a0 = H[s0 * 8 + g];
        h8 a1 = H[s1 * 8 + g];
        h8 a2 = H[s2 * 8 + g];
        h8 a3 = H[s3 * 8 + g];
        h8 a4 = H[s4 * 8 + g];
        h8 a5 = H[s5 * 8 + g];
        h8 a6 = H[s6 * 8 + g];
        h8 a7 = H[s7 * 8 + g];
#pragma unroll
        for (int i = 0; i < 8; i++) {
            acc[i] += ((float)a0[i] + (float)a1[i]) + ((float)a2[i] + (float)a3[i])
                    + ((float)a4[i] + (float)a5[i]) + ((float)a6[i] + (float)a7[i]);
        }
    }

    // self-loop
    h8 sv = H[node * 8 + g];
#pragma unroll
    for (int i = 0; i < 8; i++) acc[i] += (float)sv[i];

    // y = relu(di*acc + b1); p = y @ W2 (per-lane 8-feature partial dot)
    f4 bbA = ((const f4*)b1)[2 * g];
    f4 bbB = ((const f4*)b1)[2 * g + 1];
    float p0 = 0.f, p1 = 0.f;
#pragma unroll
    for (int i = 0; i < 8; i++) {
        float bb = (i < 4) ? bbA[i] : bbB[i - 4];
        float y = fmaxf(fmaf(acc[i], di, bb), 0.f);
        float2 w2 = *(const float2*)&W2[(8 * g + i) * N_CLASSES];
        p0 = fmaf(y, w2.x, p0);
        p1 = fmaf(y, w2.y, p1);
    }

    // reduce over the 8 feature-octets (lane0's chain uses lanes 1/2/4 only)
    p0 += __shfl_down(p0, 4, 64);
    p1 += __shfl_down(p1, 4, 64);
    p0 += __shfl_down(p0, 2, 64);
    p1 += __shfl_down(p1, 2, 64);
    p0 += __shfl_down(p0, 1, 64);
    p1 += __shfl_down(p1, 1, 64);
    if (g == 0) {
        zs[node * 2 + 0] = p0 * di;  // pre-scaled for layer-2 aggregation
        zs[node * 2 + 1] = p1 * di;
    }
}

// ---------------- agg2: 8 nodes per wave (8 lanes each) ----------------

__global__ __launch_bounds__(256) void k_agg2(
    const float* __restrict__ zs, const int* __restrict__ row_ptr,
    const int* __restrict__ rec, const float* __restrict__ dinv,
    const float* __restrict__ b2, float* __restrict__ out)
{
    const int node = blockIdx.x * 32 + (threadIdx.x >> 3);  // grid 1563
    const int j = threadIdx.x & 7;
    if (node >= N_NODES) return;
    int beg = row_ptr[node];
    int end = row_ptr[node + 1];
    float a0 = 0.f, a1 = 0.f;
    for (int idx = beg + j; idx < end; idx += 8) {
        int s = __builtin_nontemporal_load(&rec[idx]);
        float2 v = *(const float2*)&zs[s * 2];
        a0 += v.x;
        a1 += v.y;
    }
    // reduce within the 8-lane group (lane0's chain uses lanes 1/2/4 only)
    a0 += __shfl_down(a0, 4, 64);
    a1 += __shfl_down(a1, 4, 64);
    a0 += __shfl_down(a0, 2, 64);
    a1 += __shfl_down(a1, 2, 64);
    a0 += __shfl_down(a0, 1, 64);
    a1 += __shfl_down(a1, 1, 64);
    if (j == 0) {
        float di = dinv[node];
        float2 zv = *(const float2*)&zs[node * 2];
        float2 o;
        o.x = fmaf(di, a0 + zv.x, b2[0]);
        o.y = fmaf(di, a1 + zv.y, b2[1]);
        *(float2*)&out[node * 2] = o;
    }
}

// ---------------- launch ----------------

extern "C" void kernel_launch(void* const* d_in, const int* in_sizes, int n_in,
                              void* d_out, int out_size, void* d_ws, size_t ws_size,
                              hipStream_t stream) {
    const float* x  = (const float*)d_in[0];
    const int* ei   = (const int*)d_in[1];
    const float* W1 = (const float*)d_in[2];
    const float* b1 = (const float*)d_in[3];
    const float* W2 = (const float*)d_in[4];
    const float* b2 = (const float*)d_in[5];
    float* out = (float*)d_out;

    const int4* src4 = (const int4*)ei;
    const int4* dst4 = (const int4*)(ei + N_EDGES);

    // workspace layout (4-byte units), ~14 MB
    int*      bucket_off = (int*)d_ws;                   // [0, 1024)       783 used
    int*      colsum     = (int*)d_ws + 1024;            // [1024, 2048)
    float*    dinv       = (float*)d_ws + 2048;          // [2048, 52224)
    int*      row_ptr    = (int*)d_ws + 52224;           // 50001 -> pad to 102432
    int*      bhist      = (int*)d_ws + 102432;          // 196*784 = 153664 -> pad 153696
    int*      excT       = (int*)d_ws + 256128;          // 782*200 = 156400 -> pad 156448
    int*      ebin       = (int*)d_ws + 412576;          // 800000 packed ints
    int*      rec        = (int*)d_ws + 1212576;         // 800000 src ints
    _Float16* hs         = (_Float16*)((int*)d_ws + 2012576);  // 50048*64 halves
    float*    zs         = (float*)d_ws + 3614112;       // 100000 floats

    k_hist<<<NBLK, 256, 0, stream>>>(dst4, bhist);
    k_colscan<<<NBUK, 256, 0, stream>>>(bhist, excT, colsum);
    k_binA2s<<<NBLK, 256, 0, stream>>>(src4, dst4, excT, colsum, bucket_off, row_ptr, ebin);
    k_csr_gemm<<<NBUK, 256, 0, stream>>>(ebin, bucket_off, x, W1, row_ptr, dinv, rec, hs);
    k_agg1_l2<<<(N_NODES + 31) / 32, 256, 0, stream>>>(hs, row_ptr, rec, dinv, b1, W2, zs);
    k_agg2<<<(N_NODES + 31) / 32, 256, 0, stream>>>(zs, row_ptr, rec, dinv, b2, out);
}

// Round 16
// 127.999 us; speedup vs baseline: 1.1474x; 1.1474x over previous
//
#include <hip/hip_runtime.h>

#define N_NODES 50000
#define N_EDGES 800000
#define D_IN 128
#define HIDDEN 64
#define N_CLASSES 2
#define NBUK 782        // ceil(50000/64) buckets of 64 nodes
#define NBUK_P 784      // padded stride (bhist rows)
#define NBLK 196        // edge-chunk blocks: 196*4096 >= 800000
#define NBLK_P 200      // padded stride (excT rows)
#define NE4 200000      // N_EDGES/4
#define XPAD 136        // fp16 LDS row stride (128 + 8 pad)

typedef _Float16 half4v __attribute__((ext_vector_type(4)));
typedef _Float16 h8 __attribute__((ext_vector_type(8)));
typedef float f4 __attribute__((ext_vector_type(4)));

// ---------------- phase 1: per-chunk LDS histogram over dst buckets ----------------

__global__ __launch_bounds__(256) void k_hist(const int4* __restrict__ dst4,
                                              int* __restrict__ bhist) {
    __shared__ int hist[NBUK];
    int t = threadIdx.x;
    for (int i = t; i < NBUK; i += 256) hist[i] = 0;
    __syncthreads();
    int base4 = blockIdx.x * 1024;
#pragma unroll
    for (int k = 0; k < 4; k++) {
        int idx = base4 + k * 256 + t;
        if (idx < NE4) {
            int4 d = dst4[idx];
            atomicAdd(&hist[d.x >> 6], 1);
            atomicAdd(&hist[d.y >> 6], 1);
            atomicAdd(&hist[d.z >> 6], 1);
            atomicAdd(&hist[d.w >> 6], 1);
        }
    }
    __syncthreads();
    for (int i = t; i < NBUK; i += 256) bhist[blockIdx.x * NBUK_P + i] = hist[i];
}

// ---------------- phase 2: column scan over 196 chunks; excT transposed ----------------

__global__ __launch_bounds__(256) void k_colscan(const int* __restrict__ bhist,
                                                 int* __restrict__ excT,
                                                 int* __restrict__ colsum) {
    __shared__ int part[256];
    int b = blockIdx.x;   // bucket
    int t = threadIdx.x;
    int v = (t < NBLK) ? bhist[t * NBUK_P + b] : 0;
    part[t] = v;
    __syncthreads();
    for (int off = 1; off < 256; off <<= 1) {
        int p = (t >= off) ? part[t - off] : 0;
        __syncthreads();
        part[t] += p;
        __syncthreads();
    }
    if (t < NBLK) excT[b * NBLK_P + t] = part[t] - v;  // exclusive
    if (t == 255) colsum[b] = part[255];
}

// ---------------- phase 3: scatter with inline bucket-offset scan ----------------
// Each of 196 blocks redundantly scans the 782 colsums (L2-hot) -> no separate
// dispatch, no grid.sync (R9: grid.sync ~75us). pk = (src<<7)|(dst&63).
// NOTE (R15 lesson): no non-temporal hints — every buffer here is
// producer->consumer through L2; NT forces HBM round-trips (+18us).

__global__ __launch_bounds__(256) void k_binA2s(const int4* __restrict__ src4,
                                                const int4* __restrict__ dst4,
                                                const int* __restrict__ excT,
                                                const int* __restrict__ colsum,
                                                int* __restrict__ bucket_off,
                                                int* __restrict__ row_ptr,
                                                int* __restrict__ ebin) {
    __shared__ int part[256];
    __shared__ int cur[NBUK];
    const int b = blockIdx.x;
    const int t = threadIdx.x;

    int v[4];
    int s = 0;
#pragma unroll
    for (int i = 0; i < 4; i++) {
        int idx = t * 4 + i;
        v[i] = (idx < NBUK) ? colsum[idx] : 0;
        s += v[i];
    }
    part[t] = s;
    __syncthreads();
    for (int off = 1; off < 256; off <<= 1) {
        int p = (t >= off) ? part[t - off] : 0;
        __syncthreads();
        part[t] += p;
        __syncthreads();
    }
    int run = (t == 0) ? 0 : part[t - 1];
#pragma unroll
    for (int i = 0; i < 4; i++) {
        int idx = t * 4 + i;
        if (idx < NBUK) {
            cur[idx] = run + excT[idx * NBLK_P + b];
            if (b == 0) bucket_off[idx] = run;
            run += v[i];
        } else if (idx == NBUK && b == 0) {
            bucket_off[idx] = run;  // == N_EDGES
        }
    }
    if (b == 0 && t == 0) row_ptr[N_NODES] = N_EDGES;
    __syncthreads();

    int base4 = b * 1024;
#pragma unroll
    for (int k = 0; k < 4; k++) {
        int idx = base4 + k * 256 + t;
        if (idx < NE4) {
            int4 sv = src4[idx];
            int4 d = dst4[idx];
            int p0 = atomicAdd(&cur[d.x >> 6], 1);
            int p1 = atomicAdd(&cur[d.y >> 6], 1);
            int p2 = atomicAdd(&cur[d.z >> 6], 1);
            int p3 = atomicAdd(&cur[d.w >> 6], 1);
            ebin[p0] = (sv.x << 7) | (d.x & 63);
            ebin[p1] = (sv.y << 7) | (d.y & 63);
            ebin[p2] = (sv.z << 7) | (d.z & 63);
            ebin[p3] = (sv.w << 7) | (d.w & 63);
        }
    }
}

// ---------------- phase 4 (merged): per-bucket CSR + MFMA fp16 GEMM tile ----------------
// Block b owns nodes [b*64, b*64+64): builds their CSR rows, keeps dinv in LDS,
// computes hs = (x@W1)*dinv via v_mfma_f32_16x16x32_f16 (fp32 accumulate).
//   A-frag:  m = lane&15, k = (lane>>4)*8 + j
//   B-frag:  n = lane&15, k = (lane>>4)*8 + j   (W1 transposed Wt[n][k])
//   C/D:     n = lane&15, m = (lane>>4)*4 + reg

__global__ __launch_bounds__(256) void k_csr_gemm(
    const int* __restrict__ ebin, const int* __restrict__ bucket_off,
    const float* __restrict__ x, const float* __restrict__ W1,
    int* __restrict__ row_ptr, float* __restrict__ dinv_g,
    int* __restrict__ rec, _Float16* __restrict__ hs)
{
    __shared__ _Float16 xs[64 * XPAD];   // 17.0 KB
    __shared__ _Float16 Wt[64 * XPAD];   // 17.0 KB  (Wt[n][k])
    __shared__ int cnt[64];
    __shared__ int cur[64];
    __shared__ float sdinv[64];
    const int b = blockIdx.x;
    const int t = threadIdx.x;
    const int row0 = b * 64;

    // --- stage x tile fp32->fp16 ---
    for (int i4 = t; i4 < 64 * D_IN / 4; i4 += 256) {
        int r = i4 >> 5;
        int k4 = (i4 & 31) << 2;
        int grow = row0 + r;
        half4v hv;
        if (grow < N_NODES) {
            float4 v = *(const float4*)&x[grow * D_IN + k4];
            hv.x = (_Float16)v.x; hv.y = (_Float16)v.y;
            hv.z = (_Float16)v.z; hv.w = (_Float16)v.w;
        } else {
            hv.x = hv.y = hv.z = hv.w = (_Float16)0.f;  // pad rows stay zero
        }
        *(half4v*)&xs[r * XPAD + k4] = hv;
    }
    // --- stage W1 transposed fp32->fp16 ---
    for (int i4 = t; i4 < D_IN * HIDDEN / 4; i4 += 256) {
        float4 v = *(const float4*)&W1[i4 * 4];
        int k = i4 >> 4;
        int n = (i4 & 15) << 2;
        Wt[(n + 0) * XPAD + k] = (_Float16)v.x;
        Wt[(n + 1) * XPAD + k] = (_Float16)v.y;
        Wt[(n + 2) * XPAD + k] = (_Float16)v.z;
        Wt[(n + 3) * XPAD + k] = (_Float16)v.w;
    }

    // --- CSR phase: degree count + wave scan + node-sorted scatter ---
    if (t < 64) cnt[t] = 0;
    __syncthreads();
    int beg = bucket_off[b], end = bucket_off[b + 1];
    for (int i = beg + t; i < end; i += 256) atomicAdd(&cnt[ebin[i] & 63], 1);
    __syncthreads();
    if (t < 64) {
        int deg = cnt[t];
        int sum = deg;  // inclusive wave scan over 64 lanes
#pragma unroll
        for (int off = 1; off < 64; off <<= 1) {
            int v = __shfl_up(sum, off, 64);
            if (t >= off) sum += v;
        }
        int rp = beg + sum - deg;
        cur[t] = rp;
        float di = rsqrtf((float)(deg + 1));  // +1 self-loop
        sdinv[t] = di;
        int node = row0 + t;
        if (node < N_NODES) {
            row_ptr[node] = rp;
            dinv_g[node] = di;
        }
    }
    __syncthreads();
    for (int i = beg + t; i < end; i += 256) {
        int pk = ebin[i];
        int pos = atomicAdd(&cur[pk & 63], 1);
        rec[pos] = pk >> 7;
    }
    __syncthreads();  // staging + CSR complete

    // --- MFMA: wave w owns rows [w*16, w*16+16); 4 n-tiles; K=128 in 4 steps ---
    const int w = t >> 6;
    const int L = t & 63;
    const int mrow = w * 16 + (L & 15);
    const int qk = (L >> 4) * 8;
    f4 acc0 = {0.f, 0.f, 0.f, 0.f}, acc1 = acc0, acc2 = acc0, acc3 = acc0;
#pragma unroll
    for (int ks = 0; ks < D_IN; ks += 32) {
        h8 a = *(const h8*)&xs[mrow * XPAD + ks + qk];
        h8 b0 = *(const h8*)&Wt[(0 * 16 + (L & 15)) * XPAD + ks + qk];
        h8 b1 = *(const h8*)&Wt[(1 * 16 + (L & 15)) * XPAD + ks + qk];
        h8 b2 = *(const h8*)&Wt[(2 * 16 + (L & 15)) * XPAD + ks + qk];
        h8 b3 = *(const h8*)&Wt[(3 * 16 + (L & 15)) * XPAD + ks + qk];
        acc0 = __builtin_amdgcn_mfma_f32_16x16x32_f16(a, b0, acc0, 0, 0, 0);
        acc1 = __builtin_amdgcn_mfma_f32_16x16x32_f16(a, b1, acc1, 0, 0, 0);
        acc2 = __builtin_amdgcn_mfma_f32_16x16x32_f16(a, b2, acc2, 0, 0, 0);
        acc3 = __builtin_amdgcn_mfma_f32_16x16x32_f16(a, b3, acc3, 0, 0, 0);
    }

    // --- epilogue: hs[node][col] = acc * dinv ---
    const int n0 = L & 15;
#pragma unroll
    for (int j = 0; j < 4; j++) {
        int m = w * 16 + (L >> 4) * 4 + j;
        float di = sdinv[m];
        size_t base = (size_t)(row0 + m) * HIDDEN;
        hs[base + 0 * 16 + n0] = (_Float16)(acc0[j] * di);
        hs[base + 1 * 16 + n0] = (_Float16)(acc1[j] * di);
        hs[base + 2 * 16 + n0] = (_Float16)(acc2[j] * di);
        hs[base + 3 * 16 + n0] = (_Float16)(acc3[j] * di);
    }
}

// ---------------- fused agg1 + relu + layer2: 4 nodes per wave, 32 gathers in flight ----------------
// 16 lanes per node (f = feature-quad). Per 16-edge window: two unrolled groups
// of 8 independent 512B gather insts -> 32 concurrent gathers per wave.
// Reduction chains stay within each 16-lane group (lane0 reads lanes 1/2/4/8).

__global__ __launch_bounds__(256) void k_agg1_l2(
    const _Float16* __restrict__ hs, const int* __restrict__ row_ptr,
    const int* __restrict__ rec, const float* __restrict__ dinv,
    const float* __restrict__ b1, const float* __restrict__ W2,
    float* __restrict__ zs)
{
    const int node = blockIdx.x * 16 + (threadIdx.x >> 4);  // grid 3125, exact
    const int g = threadIdx.x & 15;      // lane in 16-lane group == feature quad
    const int gbase = threadIdx.x & 48;  // group's base lane within the wave
    const half4v* H = (const half4v*)hs;

    float di = dinv[node];
    float4 acc = make_float4(0.f, 0.f, 0.f, 0.f);

    int beg = row_ptr[node];
    int end = row_ptr[node + 1];

    for (int base = beg; base < end; base += 16) {
        int n = end - base;
        if (n > 16) n = 16;
        int r = N_NODES;  // pad: zero row of hs
        if (g < n) r = rec[base + g];
        int n8 = (n + 7) & ~7;
        for (int e = 0; e < n8; e += 8) {
            int i0 = gbase + e;
            int s0 = __shfl(r, i0 + 0, 64);
            int s1 = __shfl(r, i0 + 1, 64);
            int s2 = __shfl(r, i0 + 2, 64);
            int s3 = __shfl(r, i0 + 3, 64);
            int s4 = __shfl(r, i0 + 4, 64);
            int s5 = __shfl(r, i0 + 5, 64);
            int s6 = __shfl(r, i0 + 6, 64);
            int s7 = __shfl(r, i0 + 7, 64);
            half4v a0 = H[s0 * 16 + g];
            half4v a1 = H[s1 * 16 + g];
            half4v a2 = H[s2 * 16 + g];
            half4v a3 = H[s3 * 16 + g];
            half4v a4 = H[s4 * 16 + g];
            half4v a5 = H[s5 * 16 + g];
            half4v a6 = H[s6 * 16 + g];
            half4v a7 = H[s7 * 16 + g];
            acc.x += ((float)a0.x + (float)a1.x) + ((float)a2.x + (float)a3.x)
                   + ((float)a4.x + (float)a5.x) + ((float)a6.x + (float)a7.x);
            acc.y += ((float)a0.y + (float)a1.y) + ((float)a2.y + (float)a3.y)
                   + ((float)a4.y + (float)a5.y) + ((float)a6.y + (float)a7.y);
            acc.z += ((float)a0.z + (float)a1.z) + ((float)a2.z + (float)a3.z)
                   + ((float)a4.z + (float)a5.z) + ((float)a6.z + (float)a7.z);
            acc.w += ((float)a0.w + (float)a1.w) + ((float)a2.w + (float)a3.w)
                   + ((float)a4.w + (float)a5.w) + ((float)a6.w + (float)a7.w);
        }
    }

    // self-loop
    half4v sv = H[node * 16 + g];
    acc.x += (float)sv.x;
    acc.y += (float)sv.y;
    acc.z += (float)sv.z;
    acc.w += (float)sv.w;

    // y = relu(di*acc + b1); p = y @ W2 (per-lane 4-feature partial dot)
    float4 bb = ((const float4*)b1)[g];
    float4 y;
    y.x = fmaxf(fmaf(acc.x, di, bb.x), 0.f);
    y.y = fmaxf(fmaf(acc.y, di, bb.y), 0.f);
    y.z = fmaxf(fmaf(acc.z, di, bb.z), 0.f);
    y.w = fmaxf(fmaf(acc.w, di, bb.w), 0.f);
    float4 wA = ((const float4*)W2)[2 * g];      // rows 4g, 4g+1
    float4 wB = ((const float4*)W2)[2 * g + 1];  // rows 4g+2, 4g+3
    float p0 = y.x * wA.x + y.y * wA.z + y.z * wB.x + y.w * wB.z;
    float p1 = y.x * wA.y + y.y * wA.w + y.z * wB.y + y.w * wB.w;

    // reduce over the 16 feature-quads (lane0's chain uses lanes 1/2/4/8 only)
    p0 += __shfl_down(p0, 8, 64);
    p1 += __shfl_down(p1, 8, 64);
    p0 += __shfl_down(p0, 4, 64);
    p1 += __shfl_down(p1, 4, 64);
    p0 += __shfl_down(p0, 2, 64);
    p1 += __shfl_down(p1, 2, 64);
    p0 += __shfl_down(p0, 1, 64);
    p1 += __shfl_down(p1, 1, 64);
    if (g == 0) {
        zs[node * 2 + 0] = p0 * di;  // pre-scaled for layer-2 aggregation
        zs[node * 2 + 1] = p1 * di;
    }
}

// ---------------- agg2: 8 nodes per wave (8 lanes each) ----------------

__global__ __launch_bounds__(256) void k_agg2(
    const float* __restrict__ zs, const int* __restrict__ row_ptr,
    const int* __restrict__ rec, const float* __restrict__ dinv,
    const float* __restrict__ b2, float* __restrict__ out)
{
    const int node = blockIdx.x * 32 + (threadIdx.x >> 3);  // grid 1563
    const int j = threadIdx.x & 7;
    if (node >= N_NODES) return;
    int beg = row_ptr[node];
    int end = row_ptr[node + 1];
    float a0 = 0.f, a1 = 0.f;
    for (int idx = beg + j; idx < end; idx += 8) {
        int s = rec[idx];
        float2 v = *(const float2*)&zs[s * 2];
        a0 += v.x;
        a1 += v.y;
    }
    // reduce within the 8-lane group (lane0's chain uses lanes 1/2/4 only)
    a0 += __shfl_down(a0, 4, 64);
    a1 += __shfl_down(a1, 4, 64);
    a0 += __shfl_down(a0, 2, 64);
    a1 += __shfl_down(a1, 2, 64);
    a0 += __shfl_down(a0, 1, 64);
    a1 += __shfl_down(a1, 1, 64);
    if (j == 0) {
        float di = dinv[node];
        float2 zv = *(const float2*)&zs[node * 2];
        float2 o;
        o.x = fmaf(di, a0 + zv.x, b2[0]);
        o.y = fmaf(di, a1 + zv.y, b2[1]);
        *(float2*)&out[node * 2] = o;
    }
}

// ---------------- launch ----------------

extern "C" void kernel_launch(void* const* d_in, const int* in_sizes, int n_in,
                              void* d_out, int out_size, void* d_ws, size_t ws_size,
                              hipStream_t stream) {
    const float* x  = (const float*)d_in[0];
    const int* ei   = (const int*)d_in[1];
    const float* W1 = (const float*)d_in[2];
    const float* b1 = (const float*)d_in[3];
    const float* W2 = (const float*)d_in[4];
    const float* b2 = (const float*)d_in[5];
    float* out = (float*)d_out;

    const int4* src4 = (const int4*)ei;
    const int4* dst4 = (const int4*)(ei + N_EDGES);

    // workspace layout (4-byte units), ~14 MB
    int*      bucket_off = (int*)d_ws;                   // [0, 1024)       783 used
    int*      colsum     = (int*)d_ws + 1024;            // [1024, 2048)
    float*    dinv       = (float*)d_ws + 2048;          // [2048, 52224)
    int*      row_ptr    = (int*)d_ws + 52224;           // 50001 -> pad to 102432
    int*      bhist      = (int*)d_ws + 102432;          // 196*784 = 153664 -> pad 153696
    int*      excT       = (int*)d_ws + 256128;          // 782*200 = 156400 -> pad 156448
    int*      ebin       = (int*)d_ws + 412576;          // 800000 packed ints
    int*      rec        = (int*)d_ws + 1212576;         // 800000 src ints
    _Float16* hs         = (_Float16*)((int*)d_ws + 2012576);  // 50048*64 halves
    float*    zs         = (float*)d_ws + 3614112;       // 100000 floats

    k_hist<<<NBLK, 256, 0, stream>>>(dst4, bhist);
    k_colscan<<<NBUK, 256, 0, stream>>>(bhist, excT, colsum);
    k_binA2s<<<NBLK, 256, 0, stream>>>(src4, dst4, excT, colsum, bucket_off, row_ptr, ebin);
    k_csr_gemm<<<NBUK, 256, 0, stream>>>(ebin, bucket_off, x, W1, row_ptr, dinv, rec, hs);
    k_agg1_l2<<<N_NODES / 16, 256, 0, stream>>>(hs, row_ptr, rec, dinv, b1, W2, zs);
    k_agg2<<<(N_NODES + 31) / 32, 256, 0, stream>>>(zs, row_ptr, rec, dinv, b2, out);
}